// Round 1
// baseline (247.417 us; speedup 1.0000x reference)
//
#include <hip/hip_runtime.h>

#define NN 50000
#define TOPK 32
#define IN_C 128
#define OUT_C 64
#define NEG_SLOPE 0.2f
#define BN_EPS 1e-5f

// grid configs
#define K1_BLOCKS 512
#define K1_WAVES (K1_BLOCKS * 4)
#define NPG 8                       // nodes per wave-group in K1
#define N_GROUPS (NN / NPG)         // 6250 exactly
#define K2_BLOCKS 1024
#define K2_WAVES (K2_BLOCKS * 4)

// workspace layout (in floats)
#define WS_XLIN  0                       // N*64 = 3,200,000
#define WS_AI    (NN * OUT_C)            // 50,000
#define WS_AJ    (WS_AI + NN)            // 50,000
#define WS_SUMS  (WS_AJ + NN)            // 128 (sum, sumsq per channel)
#define WS_STATS (WS_SUMS + 128)         // 128 (scale, shift per channel)
// total ~12.6 MB of ws

// K1: x_lin = x @ lin_w^T  (N x 128) @ (128 x 64), plus attention coeffs
// a_i[n] = x_lin[n]Â·att_i + emb[n]Â·att_em_i ; a_j likewise.
// One wave handles 8 nodes; lane = output channel. lin_w transposed into LDS
// with +1-pad stride 65 so both the staging writes and the GEMM reads are
// bank-conflict-free (stride-1 across lanes = 2 lanes/bank = free).
__global__ __launch_bounds__(256) void k1_linear(
    const float* __restrict__ x, const float* __restrict__ emb,
    const float* __restrict__ lin_w,
    const float* __restrict__ att_i, const float* __restrict__ att_j,
    const float* __restrict__ att_em_i, const float* __restrict__ att_em_j,
    float* __restrict__ x_lin, float* __restrict__ a_i, float* __restrict__ a_j)
{
    __shared__ float wt[IN_C * (OUT_C + 1)];   // [k][c], stride 65
    const int tid = threadIdx.x;
    for (int i = tid; i < IN_C * OUT_C; i += 256) {
        int c = i >> 7;        // row of lin_w (out channel)
        int k = i & 127;       // col (in channel)
        wt[k * (OUT_C + 1) + c] = lin_w[i];
    }
    __syncthreads();

    const int lane = tid & 63;
    const int wv = __builtin_amdgcn_readfirstlane(tid >> 6);
    const int gwave = blockIdx.x * 4 + wv;

    const float ai_c = att_i[lane], aj_c = att_j[lane];
    const float aei_c = att_em_i[lane], aej_c = att_em_j[lane];

    for (int g = gwave; g < N_GROUPS; g += K1_WAVES) {
        const int base = g * NPG;
        float acc[NPG];
#pragma unroll
        for (int j = 0; j < NPG; ++j) acc[j] = 0.f;

        for (int k = 0; k < IN_C; k += 4) {
            const float w0 = wt[(k + 0) * (OUT_C + 1) + lane];
            const float w1 = wt[(k + 1) * (OUT_C + 1) + lane];
            const float w2 = wt[(k + 2) * (OUT_C + 1) + lane];
            const float w3 = wt[(k + 3) * (OUT_C + 1) + lane];
#pragma unroll
            for (int j = 0; j < NPG; ++j) {
                // wave-uniform address -> scalar loads
                const float4 xv = *(const float4*)(x + (size_t)(base + j) * IN_C + k);
                acc[j] = fmaf(xv.x, w0, acc[j]);
                acc[j] = fmaf(xv.y, w1, acc[j]);
                acc[j] = fmaf(xv.z, w2, acc[j]);
                acc[j] = fmaf(xv.w, w3, acc[j]);
            }
        }
#pragma unroll
        for (int j = 0; j < NPG; ++j) {
            const int n = base + j;
            const float y = acc[j];
            x_lin[(size_t)n * OUT_C + lane] = y;
            const float e = emb[(size_t)n * OUT_C + lane];
            float vi = y * ai_c + e * aei_c;
            float vj = y * aj_c + e * aej_c;
#pragma unroll
            for (int m = 1; m < 64; m <<= 1) {
                vi += __shfl_xor(vi, m, 64);
                vj += __shfl_xor(vj, m, 64);
            }
            if (lane == 0) { a_i[n] = vi; a_j[n] = vj; }
        }
    }
}

// K2: one wave per target node (grid-stride). Edges of node t are
// src[t*32 .. t*32+31] plus the self loop (src=t). Lanes 0..32 hold edges
// for softmax; then lane=channel for the weighted gather-accumulate.
// Also accumulates BN partial sums (channel is fixed per lane).
__global__ __launch_bounds__(256) void k2_attn(
    const int* __restrict__ src,
    const float* __restrict__ x_lin, const float* __restrict__ a_i,
    const float* __restrict__ a_j, const float* __restrict__ bias,
    float* __restrict__ out, float* __restrict__ sums)
{
    __shared__ float sdata[4 * 128];
    const int tid = threadIdx.x;
    const int lane = tid & 63;
    const int wv = __builtin_amdgcn_readfirstlane(tid >> 6);
    const int gwave = blockIdx.x * 4 + wv;
    const float bias_c = bias[lane];

    float s1 = 0.f, s2 = 0.f;

    for (int t = gwave; t < NN; t += K2_WAVES) {
        const float ai_t = a_i[t];   // wave-uniform
        int s = t;                   // lanes >= 32 default to self node
        if (lane < TOPK) s = src[t * TOPK + lane];
        float alpha = -1e30f;
        if (lane <= TOPK) {
            alpha = ai_t + a_j[s];
            alpha = alpha >= 0.f ? alpha : NEG_SLOPE * alpha;
        }
        // wave max
        float m = alpha;
#pragma unroll
        for (int d = 1; d < 64; d <<= 1) m = fmaxf(m, __shfl_xor(m, d, 64));
        float e = (lane <= TOPK) ? __expf(alpha - m) : 0.f;
        float den = e;
#pragma unroll
        for (int d = 1; d < 64; d <<= 1) den += __shfl_xor(den, d, 64);
        const float w = e / (den + 1e-16f);

        float a0 = 0.f, a1 = 0.f, a2 = 0.f, a3 = 0.f;
#pragma unroll
        for (int k = 0; k < TOPK; k += 4) {
            const float w0 = __shfl(w, k + 0, 64); const int s0 = __shfl(s, k + 0, 64);
            const float w1 = __shfl(w, k + 1, 64); const int s1i = __shfl(s, k + 1, 64);
            const float w2 = __shfl(w, k + 2, 64); const int s2i = __shfl(s, k + 2, 64);
            const float w3 = __shfl(w, k + 3, 64); const int s3 = __shfl(s, k + 3, 64);
            a0 = fmaf(w0, x_lin[(size_t)s0 * OUT_C + lane], a0);
            a1 = fmaf(w1, x_lin[(size_t)s1i * OUT_C + lane], a1);
            a2 = fmaf(w2, x_lin[(size_t)s2i * OUT_C + lane], a2);
            a3 = fmaf(w3, x_lin[(size_t)s3 * OUT_C + lane], a3);
        }
        // self loop (edge index 32)
        a0 = fmaf(__shfl(w, 32, 64), x_lin[(size_t)t * OUT_C + lane], a0);

        const float v = (a0 + a1) + (a2 + a3) + bias_c;
        out[(size_t)t * OUT_C + lane] = v;
        s1 += v;
        s2 += v * v;
    }

    sdata[wv * 128 + lane] = s1;
    sdata[wv * 128 + 64 + lane] = s2;
    __syncthreads();
    if (tid < 128) {
        const float tot = sdata[tid] + sdata[128 + tid] + sdata[256 + tid] + sdata[384 + tid];
        atomicAdd(&sums[tid], tot);
    }
}

// K3: finalize BN stats -> scale/shift per channel
__global__ __launch_bounds__(64) void k3_stats(
    const float* __restrict__ sums, const float* __restrict__ gamma,
    const float* __restrict__ beta, float* __restrict__ stats)
{
    const int c = threadIdx.x;
    const float mu = sums[c] / (float)NN;
    const float ex2 = sums[64 + c] / (float)NN;
    const float var = fmaxf(ex2 - mu * mu, 0.f);
    const float sc = gamma[c] / sqrtf(var + BN_EPS);
    stats[c] = sc;
    stats[64 + c] = beta[c] - mu * sc;
}

// K4: in-place BN apply + ReLU, float4
__global__ __launch_bounds__(256) void k4_bn(
    float* __restrict__ out, const float* __restrict__ stats)
{
    __shared__ float s_sc[64], s_sh[64];
    const int tid = threadIdx.x;
    if (tid < 64) { s_sc[tid] = stats[tid]; s_sh[tid] = stats[64 + tid]; }
    __syncthreads();
    const size_t total = (size_t)NN * OUT_C / 4;   // 800,000
    float4* p = (float4*)out;
    for (size_t idx = (size_t)blockIdx.x * 256 + tid; idx < total;
         idx += (size_t)gridDim.x * 256) {
        float4 v = p[idx];
        const int c0 = (int)((idx * 4) & 63);
        v.x = fmaxf(fmaf(v.x, s_sc[c0 + 0], s_sh[c0 + 0]), 0.f);
        v.y = fmaxf(fmaf(v.y, s_sc[c0 + 1], s_sh[c0 + 1]), 0.f);
        v.z = fmaxf(fmaf(v.z, s_sc[c0 + 2], s_sh[c0 + 2]), 0.f);
        v.w = fmaxf(fmaf(v.w, s_sc[c0 + 3], s_sh[c0 + 3]), 0.f);
        p[idx] = v;
    }
}

extern "C" void kernel_launch(void* const* d_in, const int* in_sizes, int n_in,
                              void* d_out, int out_size, void* d_ws, size_t ws_size,
                              hipStream_t stream) {
    const float* x        = (const float*)d_in[0];
    const float* emb      = (const float*)d_in[1];
    const int*   edge     = (const int*)d_in[2];   // [2, N*TOPK] int32; row 0 = src
    const float* lin_w    = (const float*)d_in[3];
    const float* att_i    = (const float*)d_in[4];
    const float* att_j    = (const float*)d_in[5];
    const float* att_em_i = (const float*)d_in[6];
    const float* att_em_j = (const float*)d_in[7];
    const float* bias     = (const float*)d_in[8];
    const float* gamma    = (const float*)d_in[9];
    const float* beta     = (const float*)d_in[10];

    float* ws    = (float*)d_ws;
    float* x_lin = ws + WS_XLIN;
    float* a_i   = ws + WS_AI;
    float* a_j   = ws + WS_AJ;
    float* sums  = ws + WS_SUMS;
    float* stats = ws + WS_STATS;
    float* out   = (float*)d_out;

    hipMemsetAsync(sums, 0, 128 * sizeof(float), stream);

    k1_linear<<<K1_BLOCKS, 256, 0, stream>>>(x, emb, lin_w, att_i, att_j,
                                             att_em_i, att_em_j, x_lin, a_i, a_j);
    k2_attn<<<K2_BLOCKS, 256, 0, stream>>>(edge, x_lin, a_i, a_j, bias, out, sums);
    k3_stats<<<1, 64, 0, stream>>>(sums, gamma, beta, stats);
    k4_bn<<<3125, 256, 0, stream>>>(out, stats);
}

// Round 2
// 216.159 us; speedup vs baseline: 1.1446x; 1.1446x over previous
//
#include <hip/hip_runtime.h>

#define NN 50000
#define TOPK 32
#define IN_C 128
#define OUT_C 64
#define NEG_SLOPE 0.2f
#define BN_EPS 1e-5f

// K1: 40 nodes per block, 10 per wave, 1250 blocks exactly
#define K1_NB 40
#define K1_NPW 10
#define K1_BLOCKS (NN / K1_NB)

// K2: 4 nodes per wave (16 lanes each)
#define K2_BLOCKS 1024
#define K2_WAVES (K2_BLOCKS * 4)
#define NTASK (NN / 4)            // 12500

// workspace layout (floats)
#define WS_XLIN  0                       // N*64
#define WS_AI    (NN * OUT_C)
#define WS_AJ    (WS_AI + NN)
#define WS_SUMS  (WS_AJ + NN)            // 128
#define WS_STATS (WS_SUMS + 128)         // 128

__device__ inline float leaky(float a) { return a >= 0.f ? a : NEG_SLOPE * a; }
__device__ inline void fma4(float4& a, float w, const float4 v) {
    a.x = fmaf(w, v.x, a.x); a.y = fmaf(w, v.y, a.y);
    a.z = fmaf(w, v.z, a.z); a.w = fmaf(w, v.w, a.w);
}
__device__ inline float dot16(const float* xr, const float4 wa, const float4 wb,
                              const float4 wc, const float4 wd, float s) {
    const float4 xa = *(const float4*)(xr);
    const float4 xb = *(const float4*)(xr + 4);
    const float4 xc = *(const float4*)(xr + 8);
    const float4 xd = *(const float4*)(xr + 12);
    s = fmaf(xa.x, wa.x, s); s = fmaf(xa.y, wa.y, s);
    s = fmaf(xa.z, wa.z, s); s = fmaf(xa.w, wa.w, s);
    s = fmaf(xb.x, wb.x, s); s = fmaf(xb.y, wb.y, s);
    s = fmaf(xb.z, wb.z, s); s = fmaf(xb.w, wb.w, s);
    s = fmaf(xc.x, wc.x, s); s = fmaf(xc.y, wc.y, s);
    s = fmaf(xc.z, wc.z, s); s = fmaf(xc.w, wc.w, s);
    s = fmaf(xd.x, wd.x, s); s = fmaf(xd.y, wd.y, s);
    s = fmaf(xd.z, wd.z, s); s = fmaf(xd.w, wd.w, s);
    return s;
}

// K1: x_lin = x @ lin_w^T plus attention coefficients a_i/a_j.
// Lane = output channel. x tile staged into LDS (coalesced), read back as
// wave-uniform broadcast ds_read_b128 (conflict-free). Weight row is
// per-lane from global (32 KB total -> L1/L2 resident after warmup).
__global__ __launch_bounds__(256) void k1_linear(
    const float* __restrict__ x, const float* __restrict__ emb,
    const float* __restrict__ lin_w,
    const float* __restrict__ att_i, const float* __restrict__ att_j,
    const float* __restrict__ att_em_i, const float* __restrict__ att_em_j,
    float* __restrict__ x_lin, float* __restrict__ a_i, float* __restrict__ a_j)
{
    __shared__ float xs[K1_NB * IN_C];
    const int tid = threadIdx.x;
    const int base = blockIdx.x * K1_NB;

    // stage 40 rows x 128 floats = 1280 float4, 5 per thread, coalesced
    float4* xs4 = (float4*)xs;
    const float4* xg = (const float4*)(x + (size_t)base * IN_C);
#pragma unroll
    for (int i = 0; i < (K1_NB * IN_C / 4) / 256; ++i)
        xs4[tid + i * 256] = xg[tid + i * 256];
    __syncthreads();

    const int lane = tid & 63;
    const int wv = tid >> 6;
    const int j0 = wv * K1_NPW;
    const float* wrow = lin_w + lane * IN_C;

    float acc[K1_NPW];
#pragma unroll
    for (int j = 0; j < K1_NPW; ++j) acc[j] = 0.f;

#pragma unroll 4
    for (int chunk = 0; chunk < IN_C / 16; ++chunk) {
        const int k = chunk * 16;
        const float4 wa = *(const float4*)(wrow + k);
        const float4 wb = *(const float4*)(wrow + k + 4);
        const float4 wc = *(const float4*)(wrow + k + 8);
        const float4 wd = *(const float4*)(wrow + k + 12);
#pragma unroll
        for (int j = 0; j < K1_NPW; ++j)
            acc[j] = dot16(xs + (j0 + j) * IN_C + k, wa, wb, wc, wd, acc[j]);
    }

    const float ai_c = att_i[lane], aj_c = att_j[lane];
    const float aei_c = att_em_i[lane], aej_c = att_em_j[lane];
#pragma unroll
    for (int j = 0; j < K1_NPW; ++j) {
        const int n = base + j0 + j;
        const float y = acc[j];
        x_lin[(size_t)n * OUT_C + lane] = y;
        const float e = emb[(size_t)n * OUT_C + lane];
        float vi = fmaf(y, ai_c, e * aei_c);
        float vj = fmaf(y, aj_c, e * aej_c);
#pragma unroll
        for (int m = 1; m < 64; m <<= 1) {
            vi += __shfl_xor(vi, m, 64);
            vj += __shfl_xor(vj, m, 64);
        }
        if (lane == 0) { a_i[n] = vi; a_j[n] = vj; }
    }
}

// K2: 4 nodes per wave; lane = (node g = lane>>4, q = lane&15).
// Each lane owns 4 channels (q*4..q*4+3). Softmax over 33 edges via two
// 16-lane passes + registered self edge. Gathers are float4: one
// instruction moves 4 nodes x 256 B rows = 1024 useful bytes.
__global__ __launch_bounds__(256) void k2_attn(
    const int* __restrict__ src,
    const float* __restrict__ x_lin, const float* __restrict__ a_i,
    const float* __restrict__ a_j, const float* __restrict__ bias,
    float* __restrict__ out, float* __restrict__ sums)
{
    const int tid = threadIdx.x;
    const int lane = tid & 63;
    const int gwave = blockIdx.x * 4 + (tid >> 6);
    const int g = lane >> 4;
    const int q = lane & 15;
    const int gb = lane & 48;          // group's base lane
    const float4 bias4 = ((const float4*)bias)[q];
    const float4* xl4 = (const float4*)x_lin;

    float4 bn1 = {0.f, 0.f, 0.f, 0.f}, bn2 = {0.f, 0.f, 0.f, 0.f};

    for (int task = gwave; task < NTASK; task += K2_WAVES) {
        const int t = task * 4 + g;
        const float ai_t = a_i[t];
        const float aj_t = a_j[t];
        const float sal = leaky(ai_t + aj_t);                 // self edge
        const int s0 = src[t * TOPK + q];
        const int s1 = src[t * TOPK + 16 + q];
        const float al0 = leaky(ai_t + a_j[s0]);
        const float al1 = leaky(ai_t + a_j[s1]);

        float m = fmaxf(al0, al1);
#pragma unroll
        for (int d = 1; d < 16; d <<= 1) m = fmaxf(m, __shfl_xor(m, d, 64));
        m = fmaxf(m, sal);
        const float e0 = __expf(al0 - m);
        const float e1 = __expf(al1 - m);
        const float es = __expf(sal - m);
        float den = e0 + e1;
#pragma unroll
        for (int d = 1; d < 16; d <<= 1) den += __shfl_xor(den, d, 64);
        den += es;
        den += 1e-16f;
        const float inv = 1.f / den;
        const float w0 = e0 * inv, w1 = e1 * inv, wself = es * inv;

        float4 A0 = {0.f,0.f,0.f,0.f}, A1 = {0.f,0.f,0.f,0.f};
        float4 A2 = {0.f,0.f,0.f,0.f}, A3 = {0.f,0.f,0.f,0.f};
#pragma unroll
        for (int e = 0; e < 16; e += 4) {
            const float we0 = __shfl(w0, gb + e, 64);     const int se0 = __shfl(s0, gb + e, 64);
            const float we1 = __shfl(w0, gb + e + 1, 64); const int se1 = __shfl(s0, gb + e + 1, 64);
            const float we2 = __shfl(w0, gb + e + 2, 64); const int se2 = __shfl(s0, gb + e + 2, 64);
            const float we3 = __shfl(w0, gb + e + 3, 64); const int se3 = __shfl(s0, gb + e + 3, 64);
            fma4(A0, we0, xl4[se0 * 16 + q]);
            fma4(A1, we1, xl4[se1 * 16 + q]);
            fma4(A2, we2, xl4[se2 * 16 + q]);
            fma4(A3, we3, xl4[se3 * 16 + q]);
        }
#pragma unroll
        for (int e = 0; e < 16; e += 4) {
            const float we0 = __shfl(w1, gb + e, 64);     const int se0 = __shfl(s1, gb + e, 64);
            const float we1 = __shfl(w1, gb + e + 1, 64); const int se1 = __shfl(s1, gb + e + 1, 64);
            const float we2 = __shfl(w1, gb + e + 2, 64); const int se2 = __shfl(s1, gb + e + 2, 64);
            const float we3 = __shfl(w1, gb + e + 3, 64); const int se3 = __shfl(s1, gb + e + 3, 64);
            fma4(A0, we0, xl4[se0 * 16 + q]);
            fma4(A1, we1, xl4[se1 * 16 + q]);
            fma4(A2, we2, xl4[se2 * 16 + q]);
            fma4(A3, we3, xl4[se3 * 16 + q]);
        }
        fma4(A0, wself, xl4[t * 16 + q]);                 // self loop

        float4 v;
        v.x = (A0.x + A1.x) + (A2.x + A3.x) + bias4.x;
        v.y = (A0.y + A1.y) + (A2.y + A3.y) + bias4.y;
        v.z = (A0.z + A1.z) + (A2.z + A3.z) + bias4.z;
        v.w = (A0.w + A1.w) + (A2.w + A3.w) + bias4.w;
        ((float4*)out)[t * 16 + q] = v;
        bn1.x += v.x; bn1.y += v.y; bn1.z += v.z; bn1.w += v.w;
        bn2.x = fmaf(v.x, v.x, bn2.x); bn2.y = fmaf(v.y, v.y, bn2.y);
        bn2.z = fmaf(v.z, v.z, bn2.z); bn2.w = fmaf(v.w, v.w, bn2.w);
    }

    // block-level BN partial reduction: channel c = q*4 + comp, slot = tid>>4
    __shared__ float s1buf[64][17];
    __shared__ float s2buf[64][17];
    const int slot = tid >> 4;     // 0..15
    s1buf[q * 4 + 0][slot] = bn1.x; s1buf[q * 4 + 1][slot] = bn1.y;
    s1buf[q * 4 + 2][slot] = bn1.z; s1buf[q * 4 + 3][slot] = bn1.w;
    s2buf[q * 4 + 0][slot] = bn2.x; s2buf[q * 4 + 1][slot] = bn2.y;
    s2buf[q * 4 + 2][slot] = bn2.z; s2buf[q * 4 + 3][slot] = bn2.w;
    __syncthreads();
    if (tid < 64) {
        float t1 = 0.f, t2 = 0.f;
#pragma unroll
        for (int r = 0; r < 16; ++r) { t1 += s1buf[tid][r]; t2 += s2buf[tid][r]; }
        atomicAdd(&sums[tid], t1);
        atomicAdd(&sums[64 + tid], t2);
    }
}

// K3: finalize BN stats -> scale/shift per channel
__global__ __launch_bounds__(64) void k3_stats(
    const float* __restrict__ sums, const float* __restrict__ gamma,
    const float* __restrict__ beta, float* __restrict__ stats)
{
    const int c = threadIdx.x;
    const float mu = sums[c] / (float)NN;
    const float ex2 = sums[64 + c] / (float)NN;
    const float var = fmaxf(ex2 - mu * mu, 0.f);
    const float sc = gamma[c] / sqrtf(var + BN_EPS);
    stats[c] = sc;
    stats[64 + c] = beta[c] - mu * sc;
}

// K4: in-place BN apply + ReLU, float4
__global__ __launch_bounds__(256) void k4_bn(
    float* __restrict__ out, const float* __restrict__ stats)
{
    __shared__ float s_sc[64], s_sh[64];
    const int tid = threadIdx.x;
    if (tid < 64) { s_sc[tid] = stats[tid]; s_sh[tid] = stats[64 + tid]; }
    __syncthreads();
    const size_t total = (size_t)NN * OUT_C / 4;
    float4* p = (float4*)out;
    for (size_t idx = (size_t)blockIdx.x * 256 + tid; idx < total;
         idx += (size_t)gridDim.x * 256) {
        float4 v = p[idx];
        const int c0 = (int)((idx * 4) & 63);
        v.x = fmaxf(fmaf(v.x, s_sc[c0 + 0], s_sh[c0 + 0]), 0.f);
        v.y = fmaxf(fmaf(v.y, s_sc[c0 + 1], s_sh[c0 + 1]), 0.f);
        v.z = fmaxf(fmaf(v.z, s_sc[c0 + 2], s_sh[c0 + 2]), 0.f);
        v.w = fmaxf(fmaf(v.w, s_sc[c0 + 3], s_sh[c0 + 3]), 0.f);
        p[idx] = v;
    }
}

extern "C" void kernel_launch(void* const* d_in, const int* in_sizes, int n_in,
                              void* d_out, int out_size, void* d_ws, size_t ws_size,
                              hipStream_t stream) {
    const float* x        = (const float*)d_in[0];
    const float* emb      = (const float*)d_in[1];
    const int*   edge     = (const int*)d_in[2];   // row 0 = src
    const float* lin_w    = (const float*)d_in[3];
    const float* att_i    = (const float*)d_in[4];
    const float* att_j    = (const float*)d_in[5];
    const float* att_em_i = (const float*)d_in[6];
    const float* att_em_j = (const float*)d_in[7];
    const float* bias     = (const float*)d_in[8];
    const float* gamma    = (const float*)d_in[9];
    const float* beta     = (const float*)d_in[10];

    float* ws    = (float*)d_ws;
    float* x_lin = ws + WS_XLIN;
    float* a_i   = ws + WS_AI;
    float* a_j   = ws + WS_AJ;
    float* sums  = ws + WS_SUMS;
    float* stats = ws + WS_STATS;
    float* out   = (float*)d_out;

    hipMemsetAsync(sums, 0, 128 * sizeof(float), stream);

    k1_linear<<<K1_BLOCKS, 256, 0, stream>>>(x, emb, lin_w, att_i, att_j,
                                             att_em_i, att_em_j, x_lin, a_i, a_j);
    k2_attn<<<K2_BLOCKS, 256, 0, stream>>>(edge, x_lin, a_i, a_j, bias, out, sums);
    k3_stats<<<1, 64, 0, stream>>>(sums, gamma, beta, stats);
    k4_bn<<<3125, 256, 0, stream>>>(out, stats);
}